// Round 13
// baseline (258.833 us; speedup 1.0000x reference)
//
#include <hip/hip_runtime.h>
#include <stdint.h>

// RNN: h_{t+1} = tanh(x_t * w_in + h_t @ W_hh^T + (b_ih+b_hh)); out = h_T @ fc_W^T + fc_b
// B = out_size (8192), T = in_sizes[0]/B (4096), H = 10.
//
// R13 design (R12 minus the last removable chain link):
//  * Wall = T x L (all batch elements in parallel waves); L is the per-step
//    serial chain. R12 measured L=169cy: ~48 issue + ~113 latency stall.
//  * Chain (minimal form): MFMA -> exp2 x3 -> add x3 -> rcp x3 -> pk2 x2 -> MFMA.
//    x now rides the MFMA C-operand: c8[s] = bias + x_s*(C*w_in), precomputed
//    per 8-step block (4 fma/step, x-only -> issues into stall windows, free).
//    Removes R12's cndmask + per-step pk2(x) from the chain; x is exact f32.
//  * Row permutation packs 10 live units into D-regs j=0..2 -> 3 exp + 3 rcp:
//    unit_of_row = {0,4,8,-1, 1,5,9,-1, 2,6,-1,-1, 3,7,-1,-1} (reg j=3 dead).
//  * r-recursion: r = 1/(1+exp2(a')), h = 1-2r; A = -2C*W_hh[perm] (fp16);
//    bias includes C*(b+rowsum(W_hh)) (the W*1 term from h=1-2r).
//  * Self-feeding MFMA: D-fragment layout == B-fragment layout (16x16x16f16).
//  * x: 8-step blocks, depth-2 software pipeline.

#define H 10

typedef __fp16 h2 __attribute__((ext_vector_type(2)));
typedef __fp16 h4 __attribute__((ext_vector_type(4)));
typedef float  f4 __attribute__((ext_vector_type(4)));

#if __has_builtin(__builtin_amdgcn_exp2f)
__device__ __forceinline__ float fast_exp2(float x) { return __builtin_amdgcn_exp2f(x); }
#else
__device__ __forceinline__ float fast_exp2(float x) { return __exp2f(x); }
#endif

#if __has_builtin(__builtin_amdgcn_rcpf)
__device__ __forceinline__ float fast_rcp(float x) { return __builtin_amdgcn_rcpf(x); }
#else
__device__ __forceinline__ float fast_rcp(float x) { return 1.0f / x; }
#endif

#if __has_builtin(__builtin_amdgcn_cvt_pkrtz)
__device__ __forceinline__ h2 pk2(float a, float b) { return __builtin_amdgcn_cvt_pkrtz(a, b); }
#else
__device__ __forceinline__ h2 pk2(float a, float b) { h2 r; r.x = (__fp16)a; r.y = (__fp16)b; return r; }
#endif

struct hpair { h2 lo, hi; };
__device__ __forceinline__ h4 mk_h4(h2 lo, h2 hi) {
    hpair p; p.lo = lo; p.hi = hi;
    return __builtin_bit_cast(h4, p);
}

// MFMA wrapper: body guarded by device-compile so BOTH passes see the same
// kernel symbol (R5 lesson: __has_builtin diverges host vs device).
__device__ __forceinline__ f4 mfma_16x16x16f16(h4 a, h4 b, f4 c) {
#if defined(__HIP_DEVICE_COMPILE__)
    return __builtin_amdgcn_mfma_f32_16x16x16f16(a, b, c, 0, 0, 0);
#else
    return c;
#endif
}

// One step. CF4: precomputed C-operand (bias + x*C*w_in). On-chain:
// MFMA, 3 exp2, 3 add, 3 rcp, 2 pk2. (d[3] dead -> compiler drops it.)
#define RNN_STEP(CF4)                                                         \
    do {                                                                      \
        f4 d = mfma_16x16x16f16(m_frag, rb, (CF4));                           \
        float e0 = fast_exp2(d[0]);                                           \
        float e1 = fast_exp2(d[1]);                                           \
        float e2 = fast_exp2(d[2]);                                           \
        rf0 = fast_rcp(e0 + 1.0f);                                            \
        rf1 = fast_rcp(e1 + 1.0f);                                            \
        rf2 = fast_rcp(e2 + 1.0f);                                            \
        rb = mk_h4(pk2(rf0, rf1), pk2(rf2, rf2));                             \
    } while (0)

// Precompute 8 C-operands from two float4 x registers (x-only -> off-chain).
#define MAKE_C8(V0, V1)                                                       \
    do {                                                                      \
        float xs_[8] = {(V0).x, (V0).y, (V0).z, (V0).w,                       \
                        (V1).x, (V1).y, (V1).z, (V1).w};                      \
        _Pragma("unroll")                                                     \
        for (int s_ = 0; s_ < 8; ++s_) {                                      \
            c8[s_][0] = __builtin_fmaf(xs_[s_], winp[0], biasc[0]);           \
            c8[s_][1] = __builtin_fmaf(xs_[s_], winp[1], biasc[1]);           \
            c8[s_][2] = __builtin_fmaf(xs_[s_], winp[2], biasc[2]);           \
            c8[s_][3] = 0.0f;                                                 \
        }                                                                     \
    } while (0)

#define STEP8()                                                               \
    do {                                                                      \
        RNN_STEP(c8[0]); RNN_STEP(c8[1]); RNN_STEP(c8[2]); RNN_STEP(c8[3]);   \
        RNN_STEP(c8[4]); RNN_STEP(c8[5]); RNN_STEP(c8[6]); RNN_STEP(c8[7]);   \
    } while (0)

__global__ __launch_bounds__(64) void rnn_mfma_perm2(
    const float* __restrict__ x,
    const float* __restrict__ W_ih,
    const float* __restrict__ W_hh,
    const float* __restrict__ b_ih,
    const float* __restrict__ b_hh,
    const float* __restrict__ fc_W,
    const float* __restrict__ fc_b,
    float* __restrict__ out,
    int B, int T)
{
    const int l = threadIdx.x;    // 0..63 (one wave per block)
    const int n = l & 15;         // batch col; also A-row index
    const int g = l >> 4;         // k sub-block
    const int b = blockIdx.x * 16 + n;

    const float C = 2.8853900817779268f;  // 2*log2(e)

    // Row/col permutation: unit_of_row[r] = original unit index or -1 (dead).
    const int uor[16] = {0, 4, 8, -1,  1, 5, 9, -1,  2, 6, -1, -1,  3, 7, -1, -1};

    // A fragment: lane (g,n) holds A[n][4g+i] = -2C*W_hh[perm] (no x column).
    const int ur = uor[n];        // this A-row's unit (or -1)
    h4 m_frag;
#pragma unroll
    for (int i = 0; i < 4; ++i) {
        const int k = 4 * g + i;
        float w = 0.0f;
        if (ur >= 0 && uor[k] >= 0) w = -2.0f * C * W_hh[ur * H + uor[k]];
        m_frag[i] = (__fp16)w;
    }

    // Per-row constants for row 4g+j: biasc = C*(b_ih+b_hh+rowsum(W_hh)),
    // winp = C*W_ih (x coefficient, applied per step in MAKE_C8), fcw = fc_W.
    float winp[4], biasc[4], fcw[4];
#pragma unroll
    for (int j = 0; j < 4; ++j) {
        const int u = uor[4 * g + j];
        float rowsum = 0.0f;
        if (u >= 0) {
#pragma unroll
            for (int k = 0; k < H; ++k) rowsum += W_hh[u * H + k];
        }
        winp[j]  = (u >= 0) ? C * W_ih[u] : 0.0f;
        biasc[j] = (u >= 0) ? C * (b_ih[u] + b_hh[u] + rowsum) : 0.0f;
        fcw[j]   = (u >= 0) ? fc_W[u] : 0.0f;
    }

    float rf0 = 0.5f, rf1 = 0.5f, rf2 = 0.5f;   // r = 0.5 <=> h = 0
    h2 halfpk = pk2(0.5f, 0.5f);
    h4 rb = mk_h4(halfpk, halfpk);
    f4 c8[8];

    const int brow = (b < B) ? b : (B - 1);
    const float* xr = x + (size_t)brow * (size_t)T;

    int t = 0;
    if (((T & 7) == 0) && T >= 24) {
        const int nb = T >> 3;
        float4 a0 = *(const float4*)(xr + 0);
        float4 a1 = *(const float4*)(xr + 4);
        float4 b0 = *(const float4*)(xr + 8);
        float4 b1 = *(const float4*)(xr + 12);
        for (int blk = 0; blk < nb - 2; ++blk) {
            const float* xf = xr + 8 * (blk + 2);
            float4 f0 = *(const float4*)(xf);
            float4 f1 = *(const float4*)(xf + 4);
            MAKE_C8(a0, a1);
            STEP8();
            a0 = b0; a1 = b1;
            b0 = f0; b1 = f1;
        }
        MAKE_C8(a0, a1);
        STEP8();
        MAKE_C8(b0, b1);
        STEP8();
        t = T;
    }
    for (; t < T; ++t) {          // generic fallback (T not multiple of 8)
        float xq = xr[t];
        f4 cg;
        cg[0] = __builtin_fmaf(xq, winp[0], biasc[0]);
        cg[1] = __builtin_fmaf(xq, winp[1], biasc[1]);
        cg[2] = __builtin_fmaf(xq, winp[2], biasc[2]);
        cg[3] = 0.0f;
        RNN_STEP(cg);
    }

    // Epilogue: h = 1 - 2r for this lane's 3 (possibly dead) units; FC+reduce.
    float acc = 0.0f;
    acc = __builtin_fmaf(__builtin_fmaf(-2.0f, rf0, 1.0f), fcw[0], acc);
    acc = __builtin_fmaf(__builtin_fmaf(-2.0f, rf1, 1.0f), fcw[1], acc);
    acc = __builtin_fmaf(__builtin_fmaf(-2.0f, rf2, 1.0f), fcw[2], acc);
    acc += __shfl_xor(acc, 16, 64);
    acc += __shfl_xor(acc, 32, 64);
    if (g == 0 && b < B) out[b] = acc + fc_b[0];
}

extern "C" void kernel_launch(void* const* d_in, const int* in_sizes, int n_in,
                              void* d_out, int out_size, void* d_ws, size_t ws_size,
                              hipStream_t stream) {
    const float* x    = (const float*)d_in[0];
    const float* W_ih = (const float*)d_in[1];
    const float* W_hh = (const float*)d_in[2];
    const float* b_ih = (const float*)d_in[3];
    const float* b_hh = (const float*)d_in[4];
    const float* fc_W = (const float*)d_in[5];
    const float* fc_b = (const float*)d_in[6];
    float* out = (float*)d_out;

    const int B = out_size;              // 8192
    const int T = in_sizes[0] / B;       // 4096

    const int blocks = (B + 15) / 16;    // one wave = 16 batch elements
    rnn_mfma_perm2<<<blocks, 64, 0, stream>>>(x, W_ih, W_hh, b_ih, b_hh,
                                              fc_W, fc_b, out, B, T);
}